// Round 3
// baseline (1030.201 us; speedup 1.0000x reference)
//
#include <hip/hip_runtime.h>
#include <hip/hip_bf16.h>

typedef __attribute__((ext_vector_type(8))) __bf16 bf16x8;
typedef __attribute__((ext_vector_type(4))) float f32x4;
typedef __attribute__((ext_vector_type(8))) unsigned short u16x8;
typedef __attribute__((ext_vector_type(4))) unsigned int u32x4;

#define DEVI static __device__ __forceinline__

DEVI unsigned short f2bf(float f) {
  unsigned u = __builtin_bit_cast(unsigned, f);
  u += 0x7fffu + ((u >> 16) & 1u);            // round-to-nearest-even
  return (unsigned short)(u >> 16);
}

DEVI bf16x8 ldbf8(const void* p) {
  return __builtin_bit_cast(bf16x8, *(const u16x8*)p);
}

DEVI void gload_lds16(const void* g, void* l) {
  __builtin_amdgcn_global_load_lds(
      (const __attribute__((address_space(1))) void*)g,
      (__attribute__((address_space(3))) void*)l, 16, 0, 0);
}

// ---------------- weight prep: W^T -> bf16, free bias ----------------
__global__ __launch_bounds__(256)
void prep_w_kernel(const float* __restrict__ Wq, const float* __restrict__ Wk,
                   const float* __restrict__ Wv, const float* __restrict__ Wo,
                   const float* __restrict__ fl,
                   unsigned short* __restrict__ wqkv,   // (2304, 768) bf16
                   unsigned short* __restrict__ wo_t,   // (768, 768) bf16
                   float* __restrict__ fb) {            // (3,64,64) f32
  const int NQKV = 2304 * 768;
  const int NO = 768 * 768;
  int idx = blockIdx.x * 256 + threadIdx.x;
  if (idx < NQKV) {
    int n = idx / 768, kk = idx - n * 768;
    int sel = n / 768;  // always 0..2
    int col = n - sel * 768;
    const float* W = (sel == 0) ? Wq : (sel == 1) ? Wk : Wv;
    wqkv[idx] = f2bf(W[kk * 768 + col]);
  } else if (idx < NQKV + NO) {
    int j = idx - NQKV;
    int n = j / 768, kk = j - n * 768;
    wo_t[j] = f2bf(Wo[kk * 768 + n]);
  } else if (idx < NQKV + NO + 3 * 64 * 64) {
    int j = idx - NQKV - NO;
    float v = fl[j];
    fb[j] = logf(1.0f / (1.0f + expf(-v)) + 1e-6f);
  }
}

// ---------------- GEMM: 128x128 tile, BK=32, 4 waves (2x2 of 64x64) ----------------
// MODE 0: A = x fp32 (65536x768), reg-staged+converted; epilogue rmsnorm + scatter to
//         q_ws/k_ws (b,h,t,d) and vt_ws (b,h,d,t), all bf16.
// MODE 1: A = y bf16 in (b,h,t,d) block layout, via global_load_lds; fp32 store to out.
template <int MODE>
__global__ __launch_bounds__(256, 2)
void gemm_kernel(const float* __restrict__ A32,
                 const unsigned short* __restrict__ Abf,
                 const unsigned short* __restrict__ Bt,  // (N,768) bf16
                 unsigned short* __restrict__ q_ws,
                 unsigned short* __restrict__ k_ws,
                 unsigned short* __restrict__ vt_ws,
                 float* __restrict__ out, int nbn) {
  __shared__ __align__(16) unsigned short As[128 * 32];
  __shared__ __align__(16) unsigned short Bs[128 * 32];
  const int tid = threadIdx.x;
  const int lane = tid & 63, wv = tid >> 6;
  const int wr = wv >> 1, wc = wv & 1;
  const int fq = lane >> 4, fr = lane & 15;
  const int bid = blockIdx.x;
  const int bn = bid % nbn, bm = bid / nbn;

  f32x4 acc[4][4];
#pragma unroll
  for (int i = 0; i < 4; ++i)
#pragma unroll
    for (int j = 0; j < 4; ++j)
#pragma unroll
      for (int e = 0; e < 4; ++e) acc[i][j][e] = 0.f;

  for (int kt = 0; kt < 24; ++kt) {
    // ---- stage B tile (128 n-rows x 32 k) via global_load_lds ----
#pragma unroll
    for (int c = 0; c < 2; ++c) {
      int lin = c * 256 + tid;
      int row = lin >> 2;
      int colb = (lin & 3) << 4;
      gload_lds16((const char*)Bt + ((size_t)(bn * 128 + row) * 768 + kt * 32) * 2 + colb,
                  (char*)Bs + c * 4096 + wv * 1024);
    }
    // ---- stage A tile ----
    if constexpr (MODE == 0) {
      int row = tid >> 1, half = tid & 1;
      const float4* src =
          (const float4*)(A32 + (size_t)(bm * 128 + row) * 768 + kt * 32 + half * 16);
      float4 a0 = src[0], a1 = src[1], a2 = src[2], a3 = src[3];
      float t0[8] = {a0.x, a0.y, a0.z, a0.w, a1.x, a1.y, a1.z, a1.w};
      float t1[8] = {a2.x, a2.y, a2.z, a2.w, a3.x, a3.y, a3.z, a3.w};
      u16x8 o0, o1;
#pragma unroll
      for (int i = 0; i < 8; ++i) { o0[i] = f2bf(t0[i]); o1[i] = f2bf(t1[i]); }
      *(u16x8*)((char*)As + row * 64 + half * 32) = o0;
      *(u16x8*)((char*)As + row * 64 + half * 32 + 16) = o1;
    } else {
#pragma unroll
      for (int c = 0; c < 2; ++c) {
        int lin = c * 256 + tid;
        int row = lin >> 2;
        int colb = (lin & 3) << 4;
        int m = bm * 128 + row;
        size_t srcb =
            ((size_t)((m >> 6) * 12 + (kt >> 1)) * 4096 + (m & 63) * 64 + (kt & 1) * 32) * 2 +
            colb;
        gload_lds16((const char*)Abf + srcb, (char*)As + c * 4096 + wv * 1024);
      }
    }
    __syncthreads();
    bf16x8 af[4], bfr[4];
#pragma unroll
    for (int i = 0; i < 4; ++i)
      af[i] = ldbf8((const char*)As + (wr * 64 + i * 16 + fr) * 64 + fq * 16);
#pragma unroll
    for (int j = 0; j < 4; ++j)
      bfr[j] = ldbf8((const char*)Bs + (wc * 64 + j * 16 + fr) * 64 + fq * 16);
#pragma unroll
    for (int i = 0; i < 4; ++i)
#pragma unroll
      for (int j = 0; j < 4; ++j)
        acc[i][j] = __builtin_amdgcn_mfma_f32_16x16x32_bf16(af[i], bfr[j], acc[i][j], 0, 0, 0);
    __syncthreads();
  }

  if constexpr (MODE == 0) {
    const int ncb = bn * 128 + wc * 64;   // wave col base (64-chunk aligned)
    const int sector = ncb / 768;         // 0=q 1=k 2=v (uniform per wave)
    const int hh = (ncb % 768) >> 6;      // head (uniform per wave)
#pragma unroll
    for (int i = 0; i < 4; ++i) {
      if (sector < 2) {
        // rmsnorm over the 64-col chunk (wave-local): reduce across the 16-lane col group
#pragma unroll
        for (int r = 0; r < 4; ++r) {
          float ss = 0.f;
#pragma unroll
          for (int j = 0; j < 4; ++j) { float v = acc[i][j][r]; ss += v * v; }
          ss += __shfl_xor(ss, 1);
          ss += __shfl_xor(ss, 2);
          ss += __shfl_xor(ss, 4);
          ss += __shfl_xor(ss, 8);
          float rms = rsqrtf(ss * 0.015625f + 1.1920929e-7f);
#pragma unroll
          for (int j = 0; j < 4; ++j) acc[i][j][r] *= rms;
        }
      }
#pragma unroll
      for (int r = 0; r < 4; ++r) {
        int m = bm * 128 + wr * 64 + i * 16 + fq * 4 + r;
        size_t base = (size_t)((m >> 6) * 12 + hh) * 4096;
        int t = m & 63;
#pragma unroll
        for (int j = 0; j < 4; ++j) {
          int d = j * 16 + fr;
          unsigned short v = f2bf(acc[i][j][r]);
          if (sector == 0) q_ws[base + t * 64 + d] = v;
          else if (sector == 1) k_ws[base + t * 64 + d] = v;
          else vt_ws[base + d * 64 + t] = v;  // V stored transposed for PV
        }
      }
    }
  } else {
#pragma unroll
    for (int i = 0; i < 4; ++i)
#pragma unroll
      for (int r = 0; r < 4; ++r) {
        int m = bm * 128 + wr * 64 + i * 16 + fq * 4 + r;
        float* op = out + (size_t)m * 768 + bn * 128 + wc * 64 + fr;
#pragma unroll
        for (int j = 0; j < 4; ++j) op[j * 16] = acc[i][j][r];
      }
  }
}

// ---------------- attention: one block per (b,h), 4 waves x 16 q-rows ----------------
DEVI float piece_bias(int h, int tq, int tk) {
  if (tq == tk) return 0.f;
  int rq = tq >> 3, cq = tq & 7;
  int rk = tk >> 3, ck = tk & 7;
  int dr = rk - rq, dc = ck - cq;
  int adr = dr < 0 ? -dr : dr, adc = dc < 0 ? -dc : dc;
  bool ok;
  if (h < 2)       ok = (adr == 1 && adc == 2) || (adr == 2 && adc == 1);  // knight
  else if (h < 4)  ok = (adr == adc);                                      // bishop (tq!=tk)
  else if (h < 6)  ok = (adr == 0) != (adc == 0);                          // rook
  else if (h == 6) ok = (adr == adc) || ((adr == 0) != (adc == 0));        // queen
  else if (h == 7) ok = (adr <= 1 && adc <= 1);                            // king (tq!=tk)
  else             ok = (dr == 1) && (adc <= 1);                           // pawn
  return ok ? 0.f : -1e30f;
}

__global__ __launch_bounds__(256, 4)
void attn_kernel(unsigned short* __restrict__ q_ws,      // in: q, out: y (block layout)
                 const unsigned short* __restrict__ k_ws,
                 const unsigned short* __restrict__ vt_ws,
                 const float* __restrict__ fb) {
  __shared__ __align__(16) unsigned short qs[4096];
  __shared__ __align__(16) unsigned short ks2[4096];
  __shared__ __align__(16) unsigned short vs[4096];
  __shared__ __align__(16) unsigned short ps[4096];
  const int bid = blockIdx.x;
  const int h = bid % 12;
  const int tid = threadIdx.x;
  const int lane = tid & 63, w = tid >> 6;
  const int fq = lane >> 4, fr = lane & 15;
  const size_t gb = (size_t)bid * 8192;  // byte base of this (b,h) 64x64 tile

  // stage q/k/vt into XOR-swizzled LDS (G4: row-major [64][128B] would be 16-way conflict)
#pragma unroll
  for (int c = 0; c < 2; ++c) {
    int byte = (c * 256 + tid) * 16;
    int row = byte >> 7;
    int colb = byte & 127;
    int sw = (row << 7) | (colb ^ ((row & 7) << 4));
    u32x4 a = *(const u32x4*)((const char*)q_ws + gb + byte);
    u32x4 b = *(const u32x4*)((const char*)k_ws + gb + byte);
    u32x4 v = *(const u32x4*)((const char*)vt_ws + gb + byte);
    *(u32x4*)((char*)qs + sw) = a;
    *(u32x4*)((char*)ks2 + sw) = b;
    *(u32x4*)((char*)vs + sw) = v;
  }
  __syncthreads();

  // S = QK^T : wave w owns q-rows w*16..w*16+15, all 64 k-cols
  f32x4 sacc[4];
#pragma unroll
  for (int j = 0; j < 4; ++j)
#pragma unroll
    for (int e = 0; e < 4; ++e) sacc[j][e] = 0.f;
#pragma unroll
  for (int kk = 0; kk < 2; ++kk) {
    int kbyte = kk * 64 + fq * 16;
    int rq = w * 16 + fr;
    bf16x8 af = ldbf8((const char*)qs + (rq << 7) + (kbyte ^ ((rq & 7) << 4)));
#pragma unroll
    for (int j = 0; j < 4; ++j) {
      int rk = j * 16 + fr;
      bf16x8 bf_ = ldbf8((const char*)ks2 + (rk << 7) + (kbyte ^ ((rk & 7) << 4)));
      sacc[j] = __builtin_amdgcn_mfma_f32_16x16x32_bf16(af, bf_, sacc[j], 0, 0, 0);
    }
  }

  // softmax (fp32): rows t1 = w*16+fq*4+r; cols tk = j*16+fr; reduce across 16-lane group
#pragma unroll
  for (int r = 0; r < 4; ++r) {
    int tq = w * 16 + fq * 4 + r;
    float s[4];
#pragma unroll
    for (int j = 0; j < 4; ++j) {
      int tk = j * 16 + fr;
      float bias = (h >= 9) ? fb[(h - 9) * 4096 + tq * 64 + tk] : piece_bias(h, tq, tk);
      s[j] = sacc[j][r] * 0.125f + bias;
    }
    float mx = fmaxf(fmaxf(s[0], s[1]), fmaxf(s[2], s[3]));
    mx = fmaxf(mx, __shfl_xor(mx, 1));
    mx = fmaxf(mx, __shfl_xor(mx, 2));
    mx = fmaxf(mx, __shfl_xor(mx, 4));
    mx = fmaxf(mx, __shfl_xor(mx, 8));
    float sum = 0.f;
#pragma unroll
    for (int j = 0; j < 4; ++j) { s[j] = __expf(s[j] - mx); sum += s[j]; }
    sum += __shfl_xor(sum, 1);
    sum += __shfl_xor(sum, 2);
    sum += __shfl_xor(sum, 4);
    sum += __shfl_xor(sum, 8);
    float inv = 1.f / sum;
#pragma unroll
    for (int j = 0; j < 4; ++j) {
      int tk = j * 16 + fr;
      *(unsigned short*)((char*)ps + (tq << 7) + ((tk * 2) ^ ((tq & 7) << 4))) =
          f2bf(s[j] * inv);
    }
  }
  __syncthreads();

  // Y = P @ V  (vs holds V^T so both operands are K(t2)-major)
  f32x4 yacc[4];
#pragma unroll
  for (int j = 0; j < 4; ++j)
#pragma unroll
    for (int e = 0; e < 4; ++e) yacc[j][e] = 0.f;
#pragma unroll
  for (int kk = 0; kk < 2; ++kk) {
    int kbyte = kk * 64 + fq * 16;
    int rp = w * 16 + fr;
    bf16x8 af = ldbf8((const char*)ps + (rp << 7) + (kbyte ^ ((rp & 7) << 4)));
#pragma unroll
    for (int j = 0; j < 4; ++j) {
      int rv = j * 16 + fr;
      bf16x8 bf_ = ldbf8((const char*)vs + (rv << 7) + (kbyte ^ ((rv & 7) << 4)));
      yacc[j] = __builtin_amdgcn_mfma_f32_16x16x32_bf16(af, bf_, yacc[j], 0, 0, 0);
    }
  }
  // write y over this block's own q_ws region (q fully consumed at staging time)
#pragma unroll
  for (int r = 0; r < 4; ++r) {
    int tq = w * 16 + fq * 4 + r;
#pragma unroll
    for (int j = 0; j < 4; ++j) {
      int d = j * 16 + fr;
      q_ws[(size_t)bid * 4096 + tq * 64 + d] = f2bf(yacc[j][r]);
    }
  }
}

extern "C" void kernel_launch(void* const* d_in, const int* in_sizes, int n_in,
                              void* d_out, int out_size, void* d_ws, size_t ws_size,
                              hipStream_t stream) {
  const float* x  = (const float*)d_in[0];
  const float* Wq = (const float*)d_in[1];
  const float* Wk = (const float*)d_in[2];
  const float* Wv = (const float*)d_in[3];
  const float* Wo = (const float*)d_in[4];
  const float* fl = (const float*)d_in[5];
  float* out = (float*)d_out;

  char* ws = (char*)d_ws;
  unsigned short* wqkv = (unsigned short*)ws;                       // 3,538,944 B
  unsigned short* wo_t = (unsigned short*)(ws + 3538944);           // 1,179,648 B
  float* fb = (float*)(ws + 3538944 + 1179648);                     // 49,152 B
  char* big = ws + 3538944 + 1179648 + 49152;                       // 16B-aligned
  unsigned short* q_ws  = (unsigned short*)big;                     // 100,663,296 B (also y)
  unsigned short* k_ws  = (unsigned short*)(big + 100663296ULL);
  unsigned short* vt_ws = (unsigned short*)(big + 201326592ULL);
  // total ws use ≈ 307 MB

  prep_w_kernel<<<9264, 256, 0, stream>>>(Wq, Wk, Wv, Wo, fl, wqkv, wo_t, fb);
  gemm_kernel<0><<<9216, 256, 0, stream>>>(x, nullptr, wqkv, q_ws, k_ws, vt_ws, nullptr, 18);
  attn_kernel<<<12288, 256, 0, stream>>>(q_ws, k_ws, vt_ws, fb);
  gemm_kernel<1><<<3072, 256, 0, stream>>>(nullptr, q_ws, wo_t, nullptr, nullptr, nullptr, out, 6);
}

// Round 4
// 866.649 us; speedup vs baseline: 1.1887x; 1.1887x over previous
//
#include <hip/hip_runtime.h>
#include <hip/hip_bf16.h>

typedef __attribute__((ext_vector_type(8))) __bf16 bf16x8;
typedef __attribute__((ext_vector_type(4))) float f32x4;
typedef __attribute__((ext_vector_type(8))) unsigned short u16x8;
typedef __attribute__((ext_vector_type(4))) unsigned int u32x4;

#define DEVI static __device__ __forceinline__

DEVI unsigned short f2bf(float f) {
  unsigned u = __builtin_bit_cast(unsigned, f);
  u += 0x7fffu + ((u >> 16) & 1u);            // round-to-nearest-even
  return (unsigned short)(u >> 16);
}

DEVI bf16x8 ldbf8(const void* p) {
  return __builtin_bit_cast(bf16x8, *(const u16x8*)p);
}

DEVI void gload_lds16(const void* g, void* l) {
  __builtin_amdgcn_global_load_lds(
      (const __attribute__((address_space(1))) void*)g,
      (__attribute__((address_space(3))) void*)l, 16, 0, 0);
}

// ---------------- x -> bf16 (into d_out scratch; dead until gemm<1>) ----------------
__global__ __launch_bounds__(256)
void prep_x_kernel(const float* __restrict__ x, unsigned short* __restrict__ xb) {
  size_t i = (size_t)(blockIdx.x * 256 + threadIdx.x) * 8;
  const float4* s = (const float4*)(x + i);
  float4 a = s[0], b = s[1];
  u16x8 o;
  o[0] = f2bf(a.x); o[1] = f2bf(a.y); o[2] = f2bf(a.z); o[3] = f2bf(a.w);
  o[4] = f2bf(b.x); o[5] = f2bf(b.y); o[6] = f2bf(b.z); o[7] = f2bf(b.w);
  *(u16x8*)(xb + i) = o;
}

// ---------------- weight prep: W^T -> bf16, free bias ----------------
__global__ __launch_bounds__(256)
void prep_w_kernel(const float* __restrict__ Wq, const float* __restrict__ Wk,
                   const float* __restrict__ Wv, const float* __restrict__ Wo,
                   const float* __restrict__ fl,
                   unsigned short* __restrict__ wqkv,   // (2304, 768) bf16
                   unsigned short* __restrict__ wo_t,   // (768, 768) bf16
                   float* __restrict__ fb) {            // (3,64,64) f32
  const int NQKV = 2304 * 768;
  const int NO = 768 * 768;
  int idx = blockIdx.x * 256 + threadIdx.x;
  if (idx < NQKV) {
    int n = idx / 768, kk = idx - n * 768;
    int sel = n / 768;
    int col = n - sel * 768;
    const float* W = (sel == 0) ? Wq : (sel == 1) ? Wk : Wv;
    wqkv[idx] = f2bf(W[kk * 768 + col]);
  } else if (idx < NQKV + NO) {
    int j = idx - NQKV;
    int n = j / 768, kk = j - n * 768;
    wo_t[j] = f2bf(Wo[kk * 768 + n]);
  } else if (idx < NQKV + NO + 3 * 64 * 64) {
    int j = idx - NQKV - NO;
    float v = fl[j];
    fb[j] = logf(1.0f / (1.0f + expf(-v)) + 1e-6f);
  }
}

// ---------------- GEMM: 128x128 tile, BK=64, 4 waves, all-gload_lds staging ----------------
// LDS layout: [128 rows][8 chunks of 16B], source pre-swizzled chunk^=(row&7) (rule 21);
// reads XOR the same -> conflict-free ds_read_b128.
// MODE 0: A = x_bf (65536,768) row-major; epilogue rmsnorm + scatter q/k/vt.
// MODE 1: A = y bf16 in (b,h,t,d) block layout (kt == head); fp32 store to out.
template <int MODE>
__global__ __launch_bounds__(256, 2)
void gemm_kernel(const unsigned short* __restrict__ A,
                 const unsigned short* __restrict__ Bt,  // (N,768) bf16
                 unsigned short* __restrict__ q_ws,
                 unsigned short* __restrict__ k_ws,
                 unsigned short* __restrict__ vt_ws,
                 float* __restrict__ out, int nbn, int cpx) {
  __shared__ __align__(16) unsigned short As[128 * 64];
  __shared__ __align__(16) unsigned short Bs[128 * 64];
  const int tid = threadIdx.x;
  const int lane = tid & 63, wv = tid >> 6;
  const int wr = wv >> 1, wc = wv & 1;
  const int fq = lane >> 4, fr = lane & 15;
  // T1: chunked XCD swizzle (nwg % 8 == 0); consecutive new-bids share one XCD's L2
  const int bid0 = blockIdx.x;
  const int bid = (bid0 & 7) * cpx + (bid0 >> 3);
  const int bn = bid % nbn, bm = bid / nbn;

  f32x4 acc[4][4];
#pragma unroll
  for (int i = 0; i < 4; ++i)
#pragma unroll
    for (int j = 0; j < 4; ++j)
#pragma unroll
      for (int e = 0; e < 4; ++e) acc[i][j][e] = 0.f;

  for (int kt = 0; kt < 12; ++kt) {
    // ---- stage A and B tiles (128 rows x 64 k each) via global_load_lds ----
#pragma unroll
    for (int c = 0; c < 4; ++c) {
      int lin = c * 256 + tid;
      int row = lin >> 3;
      int cs = (lin & 7) ^ (row & 7);     // pre-swizzled source chunk
      size_t srcA;
      if constexpr (MODE == 0) {
        srcA = ((size_t)(bm * 128 + row) * 1536) + kt * 128 + cs * 16;
      } else {
        int m = bm * 128 + row;
        srcA = ((size_t)((m >> 6) * 12 + kt) * 8192) + (size_t)(m & 63) * 128 + cs * 16;
      }
      gload_lds16((const char*)A + srcA, (char*)As + c * 4096 + wv * 1024);
      size_t srcB = ((size_t)(bn * 128 + row) * 1536) + kt * 128 + cs * 16;
      gload_lds16((const char*)Bt + srcB, (char*)Bs + c * 4096 + wv * 1024);
    }
    __syncthreads();
#pragma unroll
    for (int kk = 0; kk < 2; ++kk) {
      bf16x8 af[4], bfr[4];
#pragma unroll
      for (int i = 0; i < 4; ++i) {
        int row = wr * 64 + i * 16 + fr;
        af[i] = ldbf8((const char*)As + row * 128 + ((kk * 4 + fq) ^ (fr & 7)) * 16);
      }
#pragma unroll
      for (int j = 0; j < 4; ++j) {
        int row = wc * 64 + j * 16 + fr;
        bfr[j] = ldbf8((const char*)Bs + row * 128 + ((kk * 4 + fq) ^ (fr & 7)) * 16);
      }
#pragma unroll
      for (int i = 0; i < 4; ++i)
#pragma unroll
        for (int j = 0; j < 4; ++j)
          acc[i][j] = __builtin_amdgcn_mfma_f32_16x16x32_bf16(af[i], bfr[j], acc[i][j], 0, 0, 0);
    }
    __syncthreads();
  }

  if constexpr (MODE == 0) {
    const int ncb = bn * 128 + wc * 64;   // wave col base (64-chunk aligned)
    const int sector = ncb / 768;         // 0=q 1=k 2=v (uniform per wave)
    const int hh = (ncb % 768) >> 6;      // head (uniform per wave)
#pragma unroll
    for (int i = 0; i < 4; ++i) {
      if (sector < 2) {
        // rmsnorm over the 64-col chunk: reduce across the 16-lane col group
#pragma unroll
        for (int r = 0; r < 4; ++r) {
          float ss = 0.f;
#pragma unroll
          for (int j = 0; j < 4; ++j) { float v = acc[i][j][r]; ss += v * v; }
          ss += __shfl_xor(ss, 1);
          ss += __shfl_xor(ss, 2);
          ss += __shfl_xor(ss, 4);
          ss += __shfl_xor(ss, 8);
          float rms = rsqrtf(ss * 0.015625f + 1.1920929e-7f);
#pragma unroll
          for (int j = 0; j < 4; ++j) acc[i][j][r] *= rms;
        }
      }
#pragma unroll
      for (int r = 0; r < 4; ++r) {
        int m = bm * 128 + wr * 64 + i * 16 + fq * 4 + r;
        size_t base = (size_t)((m >> 6) * 12 + hh) * 4096;
        int t = m & 63;
#pragma unroll
        for (int j = 0; j < 4; ++j) {
          int d = j * 16 + fr;
          unsigned short v = f2bf(acc[i][j][r]);
          if (sector == 0) q_ws[base + t * 64 + d] = v;
          else if (sector == 1) k_ws[base + t * 64 + d] = v;
          else vt_ws[base + d * 64 + t] = v;  // V stored transposed for PV
        }
      }
    }
  } else {
#pragma unroll
    for (int i = 0; i < 4; ++i)
#pragma unroll
      for (int r = 0; r < 4; ++r) {
        int m = bm * 128 + wr * 64 + i * 16 + fq * 4 + r;
        float* op = out + (size_t)m * 768 + bn * 128 + wc * 64 + fr;
#pragma unroll
        for (int j = 0; j < 4; ++j) op[j * 16] = acc[i][j][r];
      }
  }
}

// ---------------- attention: one block per (b,h), 4 waves x 16 q-rows ----------------
DEVI float piece_bias(int h, int tq, int tk) {
  if (tq == tk) return 0.f;
  int rq = tq >> 3, cq = tq & 7;
  int rk = tk >> 3, ck = tk & 7;
  int dr = rk - rq, dc = ck - cq;
  int adr = dr < 0 ? -dr : dr, adc = dc < 0 ? -dc : dc;
  bool ok;
  if (h < 2)       ok = (adr == 1 && adc == 2) || (adr == 2 && adc == 1);  // knight
  else if (h < 4)  ok = (adr == adc);                                      // bishop
  else if (h < 6)  ok = (adr == 0) != (adc == 0);                          // rook
  else if (h == 6) ok = (adr == adc) || ((adr == 0) != (adc == 0));        // queen
  else if (h == 7) ok = (adr <= 1 && adc <= 1);                            // king
  else             ok = (dr == 1) && (adc <= 1);                           // pawn
  return ok ? 0.f : -1e30f;
}

__global__ __launch_bounds__(256, 4)
void attn_kernel(unsigned short* __restrict__ q_ws,      // in: q, out: y (block layout)
                 const unsigned short* __restrict__ k_ws,
                 const unsigned short* __restrict__ vt_ws,
                 const float* __restrict__ fb) {
  __shared__ __align__(16) unsigned short qs[4096];
  __shared__ __align__(16) unsigned short ks2[4096];
  __shared__ __align__(16) unsigned short vs[4096];
  __shared__ __align__(16) unsigned short ps[4096];
  const int bid = blockIdx.x;
  const int h = bid % 12;
  const int tid = threadIdx.x;
  const int lane = tid & 63, w = tid >> 6;
  const int fq = lane >> 4, fr = lane & 15;
  const size_t gb = (size_t)bid * 8192;  // byte base of this (b,h) 64x64 tile

#pragma unroll
  for (int c = 0; c < 2; ++c) {
    int byte = (c * 256 + tid) * 16;
    int row = byte >> 7;
    int colb = byte & 127;
    int sw = (row << 7) | (colb ^ ((row & 7) << 4));
    u32x4 a = *(const u32x4*)((const char*)q_ws + gb + byte);
    u32x4 b = *(const u32x4*)((const char*)k_ws + gb + byte);
    u32x4 v = *(const u32x4*)((const char*)vt_ws + gb + byte);
    *(u32x4*)((char*)qs + sw) = a;
    *(u32x4*)((char*)ks2 + sw) = b;
    *(u32x4*)((char*)vs + sw) = v;
  }
  __syncthreads();

  f32x4 sacc[4];
#pragma unroll
  for (int j = 0; j < 4; ++j)
#pragma unroll
    for (int e = 0; e < 4; ++e) sacc[j][e] = 0.f;
#pragma unroll
  for (int kk = 0; kk < 2; ++kk) {
    int kbyte = kk * 64 + fq * 16;
    int rq = w * 16 + fr;
    bf16x8 af = ldbf8((const char*)qs + (rq << 7) + (kbyte ^ ((rq & 7) << 4)));
#pragma unroll
    for (int j = 0; j < 4; ++j) {
      int rk = j * 16 + fr;
      bf16x8 bf_ = ldbf8((const char*)ks2 + (rk << 7) + (kbyte ^ ((rk & 7) << 4)));
      sacc[j] = __builtin_amdgcn_mfma_f32_16x16x32_bf16(af, bf_, sacc[j], 0, 0, 0);
    }
  }

#pragma unroll
  for (int r = 0; r < 4; ++r) {
    int tq = w * 16 + fq * 4 + r;
    float s[4];
#pragma unroll
    for (int j = 0; j < 4; ++j) {
      int tk = j * 16 + fr;
      float bias = (h >= 9) ? fb[(h - 9) * 4096 + tq * 64 + tk] : piece_bias(h, tq, tk);
      s[j] = sacc[j][r] * 0.125f + bias;
    }
    float mx = fmaxf(fmaxf(s[0], s[1]), fmaxf(s[2], s[3]));
    mx = fmaxf(mx, __shfl_xor(mx, 1));
    mx = fmaxf(mx, __shfl_xor(mx, 2));
    mx = fmaxf(mx, __shfl_xor(mx, 4));
    mx = fmaxf(mx, __shfl_xor(mx, 8));
    float sum = 0.f;
#pragma unroll
    for (int j = 0; j < 4; ++j) { s[j] = __expf(s[j] - mx); sum += s[j]; }
    sum += __shfl_xor(sum, 1);
    sum += __shfl_xor(sum, 2);
    sum += __shfl_xor(sum, 4);
    sum += __shfl_xor(sum, 8);
    float inv = 1.f / sum;
#pragma unroll
    for (int j = 0; j < 4; ++j) {
      int tk = j * 16 + fr;
      *(unsigned short*)((char*)ps + (tq << 7) + ((tk * 2) ^ ((tq & 7) << 4))) =
          f2bf(s[j] * inv);
    }
  }
  __syncthreads();

  f32x4 yacc[4];
#pragma unroll
  for (int j = 0; j < 4; ++j)
#pragma unroll
    for (int e = 0; e < 4; ++e) yacc[j][e] = 0.f;
#pragma unroll
  for (int kk = 0; kk < 2; ++kk) {
    int kbyte = kk * 64 + fq * 16;
    int rp = w * 16 + fr;
    bf16x8 af = ldbf8((const char*)ps + (rp << 7) + (kbyte ^ ((rp & 7) << 4)));
#pragma unroll
    for (int j = 0; j < 4; ++j) {
      int rv = j * 16 + fr;
      bf16x8 bf_ = ldbf8((const char*)vs + (rv << 7) + (kbyte ^ ((rv & 7) << 4)));
      yacc[j] = __builtin_amdgcn_mfma_f32_16x16x32_bf16(af, bf_, yacc[j], 0, 0, 0);
    }
  }
#pragma unroll
  for (int r = 0; r < 4; ++r) {
    int tq = w * 16 + fq * 4 + r;
#pragma unroll
    for (int j = 0; j < 4; ++j) {
      int d = j * 16 + fr;
      q_ws[(size_t)bid * 4096 + tq * 64 + d] = f2bf(yacc[j][r]);
    }
  }
}

extern "C" void kernel_launch(void* const* d_in, const int* in_sizes, int n_in,
                              void* d_out, int out_size, void* d_ws, size_t ws_size,
                              hipStream_t stream) {
  const float* x  = (const float*)d_in[0];
  const float* Wq = (const float*)d_in[1];
  const float* Wk = (const float*)d_in[2];
  const float* Wv = (const float*)d_in[3];
  const float* Wo = (const float*)d_in[4];
  const float* fl = (const float*)d_in[5];
  float* out = (float*)d_out;

  char* ws = (char*)d_ws;
  unsigned short* wqkv = (unsigned short*)ws;                       // 3,538,944 B
  unsigned short* wo_t = (unsigned short*)(ws + 3538944);           // 1,179,648 B
  float* fb = (float*)(ws + 3538944 + 1179648);                     // 49,152 B
  char* big = ws + 3538944 + 1179648 + 49152;
  unsigned short* q_ws  = (unsigned short*)big;                     // 100,663,296 B (also y)
  unsigned short* k_ws  = (unsigned short*)(big + 100663296ULL);
  unsigned short* vt_ws = (unsigned short*)(big + 201326592ULL);
  // x_bf lives in d_out (201 MB fp32 buffer; dead until gemm<1> overwrites it)
  unsigned short* x_bf = (unsigned short*)d_out;

  prep_x_kernel<<<24576, 256, 0, stream>>>(x, x_bf);
  prep_w_kernel<<<9264, 256, 0, stream>>>(Wq, Wk, Wv, Wo, fl, wqkv, wo_t, fb);
  gemm_kernel<0><<<9216, 256, 0, stream>>>(x_bf, wqkv, q_ws, k_ws, vt_ws, nullptr, 18, 1152);
  attn_kernel<<<12288, 256, 0, stream>>>(q_ws, k_ws, vt_ws, fb);
  gemm_kernel<1><<<3072, 256, 0, stream>>>(q_ws, wo_t, nullptr, nullptr, nullptr, out, 6, 384);
}